// Round 1
// baseline (6448.715 us; speedup 1.0000x reference)
//
#include <hip/hip_runtime.h>
#include <math.h>

#define NPKG   20000
#define NTGT   30000
#define NEDGE  100000
#define NTYPES 6
#define INDIM  400
#define D1C    256
#define KCL    128

__device__ __forceinline__ float lrelu(float x) { return x > 0.f ? x : 0.2f * x; }

// ---------------- utility: zero fill ----------------
__global__ void zero_f32(float* __restrict__ p, int n) {
  int i = blockIdx.x * 256 + threadIdx.x;
  int st = gridDim.x * 256;
  for (; i < n; i += st) p[i] = 0.f;
}
__global__ void zero_i32(int* __restrict__ p, int n) {
  int i = blockIdx.x * 256 + threadIdx.x;
  int st = gridDim.x * 256;
  for (; i < n; i += st) p[i] = 0;
}

// ---------------- GEMM: C[M,N] = A[M,K] @ B[K,N], row-major, 128x128 tile ----------------
// grid: (ceil(N/128), ceil(M/128), batch); strides select per-batch A/B/C.
template<bool RELU>
__global__ __launch_bounds__(256) void gemm128(const float* __restrict__ A,
                                               const float* __restrict__ B,
                                               float* __restrict__ C,
                                               int M, int K, int N,
                                               long sA, long sB, long sC) {
  __shared__ __align__(16) float As[16][136];
  __shared__ __align__(16) float Bs[16][136];
  const float* Ab = A + (long)blockIdx.z * sA;
  const float* Bb = B + (long)blockIdx.z * sB;
  float* Cb = C + (long)blockIdx.z * sC;
  const int tid = threadIdx.x;
  const int tx = tid & 15, ty = tid >> 4;   // 16 x 16 threads
  const int n0 = blockIdx.x * 128;
  const int m0 = blockIdx.y * 128;
  float acc[8][8];
#pragma unroll
  for (int i = 0; i < 8; ++i)
#pragma unroll
    for (int j = 0; j < 8; ++j) acc[i][j] = 0.f;

  for (int k0 = 0; k0 < K; k0 += 16) {
#pragma unroll
    for (int i = 0; i < 8; ++i) {            // A tile: 128 rows x 16 k
      int idx = tid + i * 256;
      int rr = idx >> 4, kk = idx & 15;
      int m = m0 + rr;
      As[kk][rr] = (m < M) ? Ab[(long)m * K + (k0 + kk)] : 0.f;
    }
#pragma unroll
    for (int i = 0; i < 8; ++i) {            // B tile: 16 k x 128 cols
      int idx = tid + i * 256;
      int kk = idx >> 7, nn = idx & 127;
      Bs[kk][nn] = Bb[(long)(k0 + kk) * N + (n0 + nn)];
    }
    __syncthreads();
#pragma unroll
    for (int kk = 0; kk < 16; ++kk) {
      float4 a0 = *(const float4*)&As[kk][ty * 8];
      float4 a1 = *(const float4*)&As[kk][ty * 8 + 4];
      float4 b0 = *(const float4*)&Bs[kk][tx * 8];
      float4 b1 = *(const float4*)&Bs[kk][tx * 8 + 4];
      float av[8] = {a0.x, a0.y, a0.z, a0.w, a1.x, a1.y, a1.z, a1.w};
      float bv[8] = {b0.x, b0.y, b0.z, b0.w, b1.x, b1.y, b1.z, b1.w};
#pragma unroll
      for (int i = 0; i < 8; ++i)
#pragma unroll
        for (int j = 0; j < 8; ++j) acc[i][j] += av[i] * bv[j];
    }
    __syncthreads();
  }
#pragma unroll
  for (int i = 0; i < 8; ++i) {
    int m = m0 + ty * 8 + i;
    if (m < M) {
#pragma unroll
      for (int j = 0; j < 8; ++j) {
        float v = acc[i][j];
        if (RELU) v = fmaxf(v, 0.f);
        Cb[(long)m * N + n0 + tx * 8 + j] = v;
      }
    }
  }
}

// ---------------- GEMM-TN (split-K, atomic): C[K1,K2] += sum_n A[rowA(n),k1]*B[rowB(n),k2]
// grid: (K2/64, K1/64, nchunks)
__global__ __launch_bounds__(256) void gemm_tn(const float* __restrict__ A,
                                               const float* __restrict__ B,
                                               float* __restrict__ C,
                                               const int* __restrict__ rowsA,
                                               const int* __restrict__ rowsB,
                                               int N, int K1, int K2, int chunk) {
  __shared__ __align__(16) float As[16][68];
  __shared__ __align__(16) float Bs[16][68];
  const int tid = threadIdx.x;
  const int tx = tid & 15, ty = tid >> 4;
  const int k2_0 = blockIdx.x * 64;
  const int k1_0 = blockIdx.y * 64;
  const int nbeg = blockIdx.z * chunk;
  const int nend = min(N, nbeg + chunk);
  float acc[4][4] = {{0.f}};

  for (int nb = nbeg; nb < nend; nb += 16) {
#pragma unroll
    for (int i = 0; i < 4; ++i) {            // 16 n x 64 k tiles for both A and B
      int idx = tid + i * 256;
      int nn = idx >> 6, kk = idx & 63;
      int n = nb + nn;
      float av = 0.f, bv = 0.f;
      if (n < nend) {
        int ra = rowsA ? rowsA[n] : n;
        int rb = rowsB ? rowsB[n] : n;
        av = A[(long)ra * K1 + k1_0 + kk];
        bv = B[(long)rb * K2 + k2_0 + kk];
      }
      As[nn][kk] = av;
      Bs[nn][kk] = bv;
    }
    __syncthreads();
#pragma unroll
    for (int nn = 0; nn < 16; ++nn) {
      float4 a = *(const float4*)&As[nn][ty * 4];
      float4 b = *(const float4*)&Bs[nn][tx * 4];
      float av[4] = {a.x, a.y, a.z, a.w};
      float bv[4] = {b.x, b.y, b.z, b.w};
#pragma unroll
      for (int i = 0; i < 4; ++i)
#pragma unroll
        for (int j = 0; j < 4; ++j) acc[i][j] += av[i] * bv[j];
    }
    __syncthreads();
  }
#pragma unroll
  for (int i = 0; i < 4; ++i)
#pragma unroll
    for (int j = 0; j < 4; ++j)
      atomicAdd(&C[(long)(k1_0 + ty * 4 + i) * K2 + k2_0 + tx * 4 + j], acc[i][j]);
}

// ---------------- CSR build ----------------
__global__ void hist_kernel(const int* __restrict__ tgt, int* __restrict__ counts,
                            int nE, int ntgt) {
  int t = blockIdx.y;
  int e = blockIdx.x * 256 + threadIdx.x;
  if (e < nE) atomicAdd(&counts[t * ntgt + tgt[(long)t * nE + e]], 1);
}

__global__ __launch_bounds__(1024) void scan_kernel(const int* __restrict__ counts_all,
                                                    int* __restrict__ offs_all,
                                                    int* __restrict__ cursor_all, int n) {
  __shared__ int lsum[1024];
  int ty = blockIdx.x;
  const int* counts = counts_all + (long)ty * n;
  int* offs = offs_all + (long)ty * (n + 1);
  int* cursor = cursor_all + (long)ty * n;
  int t = threadIdx.x;
  int chunk = (n + 1023) >> 10;
  int base = t * chunk;
  int s = 0;
  for (int i = 0; i < chunk; ++i) {
    int idx = base + i;
    if (idx < n) s += counts[idx];
  }
  lsum[t] = s;
  __syncthreads();
  for (int off = 1; off < 1024; off <<= 1) {
    int v = (t >= off) ? lsum[t - off] : 0;
    __syncthreads();
    lsum[t] += v;
    __syncthreads();
  }
  int run = lsum[t] - s;  // exclusive prefix
  for (int i = 0; i < chunk; ++i) {
    int idx = base + i;
    if (idx < n) {
      offs[idx] = run;
      cursor[idx] = run;
      run += counts[idx];
    }
  }
  if (t == 1023) offs[n] = lsum[1023];
}

__global__ void scatter_kernel(const int* __restrict__ tgt, int* __restrict__ cursor,
                               int* __restrict__ eorder, int nE, int ntgt) {
  int t = blockIdx.y;
  int e = blockIdx.x * 256 + threadIdx.x;
  if (e < nE) {
    int tv = tgt[(long)t * nE + e];
    int p = atomicAdd(&cursor[t * ntgt + tv], 1);
    eorder[(long)t * nE + p] = e;
  }
}

// ---------------- conv1: fused GATv2 segment softmax + aggregate + ReLU ----------------
// one wave per target; lane holds 4 of 256 channels; heads = 16-lane groups.
__global__ __launch_bounds__(256) void conv1_agg(const float* __restrict__ l,
                                                 const float* __restrict__ r,
                                                 const float* __restrict__ a1t,
                                                 const int* __restrict__ src,
                                                 const int* __restrict__ eorder,
                                                 const int* __restrict__ offs,
                                                 float* __restrict__ hout, int ntgt) {
  int wid = threadIdx.x >> 6, lane = threadIdx.x & 63;
  int v = blockIdx.x * 4 + wid;
  if (v >= ntgt) return;
  const float4 re = *(const float4*)(r + (long)v * 256 + lane * 4);
  const float4 aa = *(const float4*)(a1t + lane * 4);
  int beg = offs[v], end = offs[v + 1];
  float ax = 0.f, ay = 0.f, az = 0.f, aw = 0.f, den = 0.f;
  for (int p = beg; p < end; ++p) {
    int e = eorder[p];
    int u = src[e];
    const float4 le = *(const float4*)(l + (long)u * 256 + lane * 4);
    float s = lrelu(le.x + re.x) * aa.x + lrelu(le.y + re.y) * aa.y +
              lrelu(le.z + re.z) * aa.z + lrelu(le.w + re.w) * aa.w;
#pragma unroll
    for (int m = 1; m < 16; m <<= 1) s += __shfl_xor(s, m, 64);  // per-head (64ch) sum
    float w = expf(s);   // scores are O(1): no max-subtract needed
    ax += w * le.x; ay += w * le.y; az += w * le.z; aw += w * le.w;
    den += w;
  }
  float inv = (end > beg) ? 1.f / den : 0.f;
  float4 o;
  o.x = fmaxf(ax * inv, 0.f);
  o.y = fmaxf(ay * inv, 0.f);
  o.z = fmaxf(az * inv, 0.f);
  o.w = fmaxf(aw * inv, 0.f);
  *(float4*)(hout + (long)v * 256 + lane * 4) = o;
}

// ---------------- row softmax over 128 cols (in place) + entropy accumulation ----------------
__global__ __launch_bounds__(256) void softmax_ent(float* __restrict__ S, int nrows,
                                                   float inv_n, float* __restrict__ ent_slots) {
  int wid = threadIdx.x >> 6, lane = threadIdx.x & 63;
  int v = blockIdx.x * 4 + wid;
  if (v >= nrows) return;
  float* row = S + (long)v * 128;
  float x0 = row[lane], x1 = row[lane + 64];
  float m = fmaxf(x0, x1);
#pragma unroll
  for (int sh = 1; sh < 64; sh <<= 1) m = fmaxf(m, __shfl_xor(m, sh, 64));
  float e0 = expf(x0 - m), e1 = expf(x1 - m);
  float s = e0 + e1;
  float t = e0 * (x0 - m) + e1 * (x1 - m);
#pragma unroll
  for (int sh = 1; sh < 64; sh <<= 1) {
    s += __shfl_xor(s, sh, 64);
    t += __shfl_xor(t, sh, 64);
  }
  float inv = 1.f / s;
  row[lane] = e0 * inv;
  row[lane + 64] = e1 * inv;
  if (lane == 0) {
    float ent = logf(s) - t / s;  // = -sum p log p
    atomicAdd(&ent_slots[blockIdx.x & 255], ent * inv_n);
  }
}

// ---------------- link loss: norm2 = E - 2*trace(Apool) + sum(Mp*Mt) ----------------
__global__ __launch_bounds__(256) void link_kernel(const float* __restrict__ Apool,
                                                   const float* __restrict__ Mp,
                                                   const float* __restrict__ Mt,
                                                   float Ef, float scale,
                                                   float* __restrict__ loss) {
  __shared__ float red[256];
  int t = threadIdx.x;
  float s = 0.f;
  for (int i = t; i < 16384; i += 256) s += Mp[i] * Mt[i];
  if (t < 128) s -= 2.f * Apool[t * 129];  // diag: trace = dot(Ss,St) summed
  red[t] = s;
  __syncthreads();
  for (int sh = 128; sh > 0; sh >>= 1) {
    if (t < sh) red[t] += red[t + sh];
    __syncthreads();
  }
  if (t == 0) {
    float norm2 = Ef + red[0];
    atomicAdd(loss, sqrtf(fmaxf(norm2, 0.f) + 1e-12f) * scale);
  }
}

// ---------------- conv2 dense attention: scores + mask + softmax over source clusters ----------------
// grid (128 j, 6 t); block 256
__global__ __launch_bounds__(256) void conv2_attn(const float* __restrict__ l2_all,
                                                  const float* __restrict__ r2_all,
                                                  const float* __restrict__ Apool_all,
                                                  const float* __restrict__ a2_all,
                                                  float* __restrict__ attn_out) {
  __shared__ float r2row[256], a2s[256], sc[512];
  int j = blockIdx.x;
  int t = blockIdx.y;
  int tid = threadIdx.x;
  const float* l2 = l2_all + (long)t * 32768;
  const float* Apool = Apool_all + (long)t * 16384;
  r2row[tid] = r2_all[(long)t * 32768 + j * 256 + tid];
  a2s[tid] = a2_all[t * 256 + tid];
  __syncthreads();
#pragma unroll
  for (int p = tid; p < 512; p += 256) {
    int i = p >> 2, h = p & 3;
    const float* lr_ = l2 + i * 256 + h * 64;
    const float* rr_ = r2row + h * 64;
    const float* av_ = a2s + h * 64;
    float s = 0.f;
    for (int c = 0; c < 64; ++c) {
      float x = lr_[c] + rr_[c];
      s += (x > 0.f ? x : 0.2f * x) * av_[c];
    }
    sc[p] = (Apool[i * 128 + j] > 0.f) ? s : -1e9f;
  }
  __syncthreads();
  int h = tid >> 6, lane = tid & 63;
  float v0 = sc[lane * 4 + h], v1 = sc[(lane + 64) * 4 + h];
  float m = fmaxf(v0, v1);
#pragma unroll
  for (int sh = 1; sh < 64; sh <<= 1) m = fmaxf(m, __shfl_xor(m, sh, 64));
  float e0 = expf(v0 - m), e1 = expf(v1 - m);
  float s = e0 + e1;
#pragma unroll
  for (int sh = 1; sh < 64; sh <<= 1) s += __shfl_xor(s, sh, 64);
  float inv = 1.f / s;
  attn_out[(long)t * 65536 + (long)lane * 512 + j * 4 + h] = e0 * inv;
  attn_out[(long)t * 65536 + (long)(lane + 64) * 512 + j * 4 + h] = e1 * inv;
}

// ---------------- classifier: sigmoid(p_all @ Wcls + b) ----------------
__global__ __launch_bounds__(256) void classifier(const float* __restrict__ p_all,
                                                  const float* __restrict__ Wcls,
                                                  const float* __restrict__ bcls,
                                                  float* __restrict__ out, int nrows) {
  int wid = threadIdx.x >> 6, lane = threadIdx.x & 63;
  int rrow = blockIdx.x * 4 + wid;
  if (rrow >= nrows) return;
  const float4 w = *(const float4*)(Wcls + lane * 4);
  const float4 x = *(const float4*)(p_all + (long)rrow * 256 + lane * 4);
  float s = x.x * w.x + x.y * w.y + x.z * w.z + x.w * w.w;
#pragma unroll
  for (int sh = 1; sh < 64; sh <<= 1) s += __shfl_xor(s, sh, 64);
  if (lane == 0) out[rrow] = 1.f / (1.f + expf(-(s + bcls[0])));
}

__global__ void finalize_loss(const float* __restrict__ red_buf, float* __restrict__ out896) {
  __shared__ float red[256];
  int t = threadIdx.x;
  red[t] = red_buf[t];
  __syncthreads();
  for (int sh = 128; sh > 0; sh >>= 1) {
    if (t < sh) red[t] += red[t + sh];
    __syncthreads();
  }
  if (t == 0) out896[0] = red[0] + red_buf[256];  // ent sum + link accum
}

// =====================================================================
extern "C" void kernel_launch(void* const* d_in, const int* in_sizes, int n_in,
                              void* d_out, int out_size, void* d_ws, size_t ws_size,
                              hipStream_t stream) {
  (void)in_sizes; (void)n_in; (void)out_size; (void)ws_size;
  const float* x_pkg  = (const float*)d_in[0];
  const float* x_tgt  = (const float*)d_in[1];
  const int* src_idx  = (const int*)d_in[2];
  const int* tgt_idx  = (const int*)d_in[3];
  const float* W1s    = (const float*)d_in[4];
  const float* W1t    = (const float*)d_in[5];
  const float* a1     = (const float*)d_in[6];
  const float* Wpkg   = (const float*)d_in[7];
  const float* Wassign= (const float*)d_in[8];
  const float* W2s    = (const float*)d_in[9];
  const float* W2t    = (const float*)d_in[10];
  const float* a2     = (const float*)d_in[11];
  const float* Wcls   = (const float*)d_in[12];
  const float* bcls   = (const float*)d_in[13];
  float* out = (float*)d_out;

  char* wp = (char*)d_ws;
  auto alloc = [&](size_t bytes) -> char* {
    char* r = wp;
    wp += (bytes + 255) & ~(size_t)255;
    return r;
  };
  float* h_pkg   = (float*)alloc((size_t)NPKG * 256 * 4);
  float* l_buf   = (float*)alloc((size_t)NPKG * 256 * 4);
  float* r_buf   = (float*)alloc((size_t)NTGT * 256 * 4);
  float* h_t     = (float*)alloc((size_t)NTGT * 256 * 4);
  float* S_pkg   = (float*)alloc((size_t)NPKG * 128 * 4);
  float* S_t     = (float*)alloc((size_t)NTGT * 128 * 4);
  float* p_buf   = (float*)alloc((size_t)7 * 128 * 256 * 4);    // p_pkg + 6x p_tgt
  float* M_pkg   = (float*)alloc(16384 * 4);
  float* Mt      = (float*)alloc(16384 * 4);
  float* Apool   = (float*)alloc((size_t)NTYPES * 16384 * 4);
  float* l2_all  = (float*)alloc((size_t)NTYPES * 32768 * 4);
  float* r2_all  = (float*)alloc((size_t)NTYPES * 32768 * 4);
  float* red_buf = (float*)alloc(257 * 4);                      // [0..255]=ent slots, [256]=link
  int* counts    = (int*)alloc((size_t)NTYPES * NTGT * 4);
  int* offs      = (int*)alloc((size_t)NTYPES * (NTGT + 1) * 4);
  int* cursor    = (int*)alloc((size_t)NTYPES * NTGT * 4);
  int* eorder    = (int*)alloc((size_t)NTYPES * NEDGE * 4);
  float* ent_slots = red_buf;
  float* loss_acc  = red_buf + 256;

  dim3 blk(256);

  // --- init atomic targets ---
  zero_f32<<<dim3(64), blk, 0, stream>>>(p_buf, 7 * 128 * 256);
  zero_f32<<<dim3(16), blk, 0, stream>>>(M_pkg, 16384);
  zero_f32<<<dim3(96), blk, 0, stream>>>(Apool, NTYPES * 16384);
  zero_f32<<<dim3(1), blk, 0, stream>>>(red_buf, 257);
  zero_i32<<<dim3(180), blk, 0, stream>>>(counts, NTYPES * NTGT);

  // --- CSR for all 6 edge types ---
  hist_kernel<<<dim3(391, NTYPES), blk, 0, stream>>>(tgt_idx, counts, NEDGE, NTGT);
  scan_kernel<<<dim3(NTYPES), dim3(1024), 0, stream>>>(counts, offs, cursor, NTGT);
  scatter_kernel<<<dim3(391, NTYPES), blk, 0, stream>>>(tgt_idx, cursor, eorder, NEDGE, NTGT);

  // --- package branch ---
  gemm128<true><<<dim3(2, 157, 1), blk, 0, stream>>>(x_pkg, Wpkg, h_pkg, NPKG, INDIM, 256, 0, 0, 0);
  gemm128<false><<<dim3(1, 157, 1), blk, 0, stream>>>(h_pkg, Wassign, S_pkg, NPKG, 256, 128, 0, 0, 0);
  softmax_ent<<<dim3(5000), blk, 0, stream>>>(S_pkg, NPKG, 1.f / NPKG, ent_slots);
  gemm_tn<<<dim3(4, 2, 40), blk, 0, stream>>>(S_pkg, h_pkg, p_buf, nullptr, nullptr, NPKG, 128, 256, 512);
  gemm_tn<<<dim3(2, 2, 40), blk, 0, stream>>>(S_pkg, S_pkg, M_pkg, nullptr, nullptr, NPKG, 128, 128, 512);

  // --- per edge type ---
  for (int t = 0; t < NTYPES; ++t) {
    const int* srct = src_idx + (long)t * NEDGE;
    const int* tgtt = tgt_idx + (long)t * NEDGE;
    gemm128<false><<<dim3(2, 157, 1), blk, 0, stream>>>(
        x_pkg, W1s + (long)t * INDIM * 256, l_buf, NPKG, INDIM, 256, 0, 0, 0);
    gemm128<false><<<dim3(2, 235, 1), blk, 0, stream>>>(
        x_tgt + (long)t * NTGT * INDIM, W1t + (long)t * INDIM * 256, r_buf, NTGT, INDIM, 256, 0, 0, 0);
    conv1_agg<<<dim3(7500), blk, 0, stream>>>(l_buf, r_buf, a1 + t * 256, srct,
                                              eorder + (long)t * NEDGE,
                                              offs + (long)t * (NTGT + 1), h_t, NTGT);
    gemm128<false><<<dim3(1, 235, 1), blk, 0, stream>>>(
        h_t, Wassign + (long)(t + 1) * 256 * 128, S_t, NTGT, 256, 128, 0, 0, 0);
    softmax_ent<<<dim3(7500), blk, 0, stream>>>(S_t, NTGT, 1.f / NTGT, ent_slots);
    gemm_tn<<<dim3(4, 2, 59), blk, 0, stream>>>(S_t, h_t, p_buf + (long)(t + 1) * 32768,
                                                nullptr, nullptr, NTGT, 128, 256, 512);
    zero_f32<<<dim3(16), blk, 0, stream>>>(Mt, 16384);
    gemm_tn<<<dim3(2, 2, 59), blk, 0, stream>>>(S_t, S_t, Mt, nullptr, nullptr, NTGT, 128, 128, 512);
    gemm_tn<<<dim3(2, 2, 196), blk, 0, stream>>>(S_pkg, S_t, Apool + (long)t * 16384,
                                                 srct, tgtt, NEDGE, 128, 128, 512);
    link_kernel<<<dim3(1), blk, 0, stream>>>(Apool + (long)t * 16384, M_pkg, Mt,
                                             (float)NEDGE, 1.f / ((float)NPKG * (float)NTGT),
                                             loss_acc);
  }

  // --- conv2 attention (batched over types) ---
  gemm128<false><<<dim3(2, 1, NTYPES), blk, 0, stream>>>(p_buf, W2s, l2_all, 128, 256, 256,
                                                         0, 65536, 32768);
  gemm128<false><<<dim3(2, 1, NTYPES), blk, 0, stream>>>(p_buf + 32768, W2t, r2_all, 128, 256, 256,
                                                         32768, 65536, 32768);
  conv2_attn<<<dim3(128, NTYPES), blk, 0, stream>>>(l2_all, r2_all, Apool, a2, out + 897);

  // --- classifier + loss ---
  classifier<<<dim3(224), blk, 0, stream>>>(p_buf, Wcls, bcls, out, 896);
  finalize_loss<<<dim3(1), blk, 0, stream>>>(red_buf, out + 896);
}

// Round 2
// 3193.808 us; speedup vs baseline: 2.0191x; 2.0191x over previous
//
#include <hip/hip_runtime.h>
#include <math.h>

#define NPKG   20000
#define NTGT   30000
#define NEDGE  100000
#define NTYPES 6
#define INDIM  400
#define KP_IN  416      // INDIM padded to mult of 32
#define MP_PKG 20096    // 157*128
#define MP_TGT 30080    // 235*128

typedef unsigned short ushortT;
typedef __attribute__((ext_vector_type(8))) short bf16x8;
typedef __attribute__((ext_vector_type(4))) float f32x4;

__device__ __forceinline__ float lrelu(float x) { return x > 0.f ? x : 0.2f * x; }
__device__ __forceinline__ float b2f(ushortT u) {
  union { unsigned int i; float f; } x; x.i = ((unsigned int)u) << 16; return x.f;
}
__device__ __forceinline__ ushortT f2b(float f) {
  unsigned int u = __float_as_uint(f);
  unsigned int r = (u + 0x7FFFu + ((u >> 16) & 1u)) >> 16;
  return (ushortT)r;
}

#define GLL16(g, l)                                                            \
  __builtin_amdgcn_global_load_lds(                                            \
      (const __attribute__((address_space(1))) void*)(g),                      \
      (__attribute__((address_space(3))) void*)(l), 16, 0, 0)

// ---------------- utility ----------------
__global__ void zero_f32(float* __restrict__ p, int n) {
  int i = blockIdx.x * 256 + threadIdx.x, st = gridDim.x * 256;
  for (; i < n; i += st) p[i] = 0.f;
}
__global__ void zero_i32(int* __restrict__ p, int n) {
  int i = blockIdx.x * 256 + threadIdx.x, st = gridDim.x * 256;
  for (; i < n; i += st) p[i] = 0;
}

// f32 [M,K] -> bf16 [*, Kp], zero-pad cols K..Kp (rows >= M untouched)
__global__ void convert_pad(const float* __restrict__ src, ushortT* __restrict__ dst,
                            int M, int K, int Kp) {
  int idx = blockIdx.x * 256 + threadIdx.x;
  int q = Kp >> 2;
  int row = idx / q, c4 = (idx - row * q) * 4;
  if (row >= M) return;
  float4 v = make_float4(0.f, 0.f, 0.f, 0.f);
  if (c4 < K) v = *(const float4*)(src + (size_t)row * K + c4);  // K mult of 4
  ushort4 o;
  o.x = f2b(v.x); o.y = f2b(v.y); o.z = f2b(v.z); o.w = f2b(v.w);
  *(ushort4*)(dst + (size_t)row * Kp + c4) = o;
}

// W [K,N] f32 -> WT [N,Kp] bf16, zero-pad; batched over blockIdx.y
__global__ void wtrans(const float* __restrict__ W, ushortT* __restrict__ WT,
                       int K, int N, int Kp) {
  long b = blockIdx.y;
  const float* Wb = W + b * (long)K * N;
  ushortT* WTb = WT + b * (long)N * Kp;
  int idx = blockIdx.x * 256 + threadIdx.x;
  if (idx >= N * Kp) return;
  int n = idx / Kp, k = idx - n * Kp;
  WTb[idx] = (k < K) ? f2b(Wb[(long)k * N + n]) : (ushortT)0;
}

// ---------------- MFMA GEMM: C[M,N] = A[M,Kp](bf16) @ BT[N,Kp]^T(bf16) ----------------
// 128x128 tile, 4 waves of 64x64, 16x16x32 bf16 MFMA, global_load_lds staging.
template<bool RELU, bool WF32, bool WB16>
__global__ __launch_bounds__(256) void gemm_mfma(const ushortT* __restrict__ A,
                                                 const ushortT* __restrict__ BT,
                                                 float* __restrict__ Cf,
                                                 ushortT* __restrict__ Cb,
                                                 int M, int Kp, int N) {
  __shared__ ushortT As[128 * 32];
  __shared__ ushortT Bs[128 * 32];
  const int tid = threadIdx.x;
  const int wave = tid >> 6, lane = tid & 63;
  const int lr = lane & 15, hk = lane >> 4;
  const int am = (wave >> 1) * 64;     // wave row block
  const int bn = (wave & 1) * 64;      // wave col block
  const int m0 = blockIdx.y * 128;
  const int n0 = blockIdx.x * 128;

  // staging slots: slot s (0..511) -> row s>>2, col-group s&3 (8 bf16 = 16B)
  const int row1 = tid >> 2, cg = (tid & 3) * 8;
  const int row2 = row1 + 64;
  ushortT* ldsA1 = As + ((tid >> 6) << 9);
  ushortT* ldsA2 = As + 2048 + ((tid >> 6) << 9);
  ushortT* ldsB1 = Bs + ((tid >> 6) << 9);
  ushortT* ldsB2 = Bs + 2048 + ((tid >> 6) << 9);
  const ushortT* gA1 = A + (size_t)(m0 + row1) * Kp + cg;
  const ushortT* gA2 = A + (size_t)(m0 + row2) * Kp + cg;
  const ushortT* gB1 = BT + (size_t)(n0 + row1) * Kp + cg;
  const ushortT* gB2 = BT + (size_t)(n0 + row2) * Kp + cg;

  f32x4 acc[4][4];
#pragma unroll
  for (int i = 0; i < 4; ++i)
#pragma unroll
    for (int j = 0; j < 4; ++j) acc[i][j] = (f32x4)(0.f);

  const int nk = Kp >> 5;
  for (int kt = 0; kt < nk; ++kt) {
    const int k0 = kt << 5;
    GLL16(gA1 + k0, ldsA1);
    GLL16(gA2 + k0, ldsA2);
    GLL16(gB1 + k0, ldsB1);
    GLL16(gB2 + k0, ldsB2);
    __syncthreads();
    bf16x8 af[4], bfr[4];
#pragma unroll
    for (int i = 0; i < 4; ++i)
      af[i] = *(const bf16x8*)(As + (size_t)(am + i * 16 + lr) * 32 + hk * 8);
#pragma unroll
    for (int j = 0; j < 4; ++j)
      bfr[j] = *(const bf16x8*)(Bs + (size_t)(bn + j * 16 + lr) * 32 + hk * 8);
#pragma unroll
    for (int i = 0; i < 4; ++i)
#pragma unroll
      for (int j = 0; j < 4; ++j)
        acc[i][j] = __builtin_amdgcn_mfma_f32_16x16x32_bf16(af[i], bfr[j], acc[i][j], 0, 0, 0);
    __syncthreads();
  }

#pragma unroll
  for (int i = 0; i < 4; ++i) {
#pragma unroll
    for (int reg = 0; reg < 4; ++reg) {
      int row = m0 + am + i * 16 + hk * 4 + reg;
      if (row < M) {
#pragma unroll
        for (int j = 0; j < 4; ++j) {
          int col = n0 + bn + j * 16 + lr;
          float v = acc[i][j][reg];
          if (RELU) v = fmaxf(v, 0.f);
          if (WF32) Cf[(size_t)row * N + col] = v;
          if (WB16) Cb[(size_t)row * N + col] = f2b(v);
        }
      }
    }
  }
}

// ---------------- f32 SIMT GEMM (kept for tiny conv2 gemms) ----------------
template<bool RELU>
__global__ __launch_bounds__(256) void gemm128(const float* __restrict__ A,
                                               const float* __restrict__ B,
                                               float* __restrict__ C,
                                               int M, int K, int N,
                                               long sA, long sB, long sC) {
  __shared__ __align__(16) float As[16][136];
  __shared__ __align__(16) float Bs[16][136];
  const float* Ab = A + (long)blockIdx.z * sA;
  const float* Bb = B + (long)blockIdx.z * sB;
  float* Cb = C + (long)blockIdx.z * sC;
  const int tid = threadIdx.x;
  const int tx = tid & 15, ty = tid >> 4;
  const int n0 = blockIdx.x * 128, m0 = blockIdx.y * 128;
  float acc[8][8];
#pragma unroll
  for (int i = 0; i < 8; ++i)
#pragma unroll
    for (int j = 0; j < 8; ++j) acc[i][j] = 0.f;
  for (int k0 = 0; k0 < K; k0 += 16) {
#pragma unroll
    for (int i = 0; i < 8; ++i) {
      int idx = tid + i * 256;
      int rr = idx >> 4, kk = idx & 15;
      int m = m0 + rr;
      As[kk][rr] = (m < M) ? Ab[(long)m * K + (k0 + kk)] : 0.f;
    }
#pragma unroll
    for (int i = 0; i < 8; ++i) {
      int idx = tid + i * 256;
      int kk = idx >> 7, nn = idx & 127;
      Bs[kk][nn] = Bb[(long)(k0 + kk) * N + (n0 + nn)];
    }
    __syncthreads();
#pragma unroll
    for (int kk = 0; kk < 16; ++kk) {
      float4 a0 = *(const float4*)&As[kk][ty * 8];
      float4 a1 = *(const float4*)&As[kk][ty * 8 + 4];
      float4 b0 = *(const float4*)&Bs[kk][tx * 8];
      float4 b1 = *(const float4*)&Bs[kk][tx * 8 + 4];
      float av[8] = {a0.x, a0.y, a0.z, a0.w, a1.x, a1.y, a1.z, a1.w};
      float bv[8] = {b0.x, b0.y, b0.z, b0.w, b1.x, b1.y, b1.z, b1.w};
#pragma unroll
      for (int i = 0; i < 8; ++i)
#pragma unroll
        for (int j = 0; j < 8; ++j) acc[i][j] += av[i] * bv[j];
    }
    __syncthreads();
  }
#pragma unroll
  for (int i = 0; i < 8; ++i) {
    int m = m0 + ty * 8 + i;
    if (m < M) {
#pragma unroll
      for (int j = 0; j < 8; ++j) {
        float v = acc[i][j];
        if (RELU) v = fmaxf(v, 0.f);
        Cb[(long)m * N + n0 + tx * 8 + j] = v;
      }
    }
  }
}

// ---------------- GEMM-TN bf16 (split-K atomic): C[K1,K2] += sum_n A[rA(n),k1]*B[rB(n),k2]
__global__ __launch_bounds__(256) void gemm_tn_bf(const ushortT* __restrict__ A,
                                                  const ushortT* __restrict__ B,
                                                  float* __restrict__ C,
                                                  const int* __restrict__ rowsA,
                                                  const int* __restrict__ rowsB,
                                                  int N, int K1, int K2, int chunk) {
  __shared__ __align__(16) float As[16][68];
  __shared__ __align__(16) float Bs[16][68];
  const int tid = threadIdx.x;
  const int tx = tid & 15, ty = tid >> 4;
  const int k2_0 = blockIdx.x * 64, k1_0 = blockIdx.y * 64;
  const int nbeg = blockIdx.z * chunk;
  const int nend = min(N, nbeg + chunk);
  float acc[4][4] = {{0.f}};
  const int nn_ = tid >> 4, kk4 = (tid & 15) * 4;

  for (int nb = nbeg; nb < nend; nb += 16) {
    int n = nb + nn_;
    float a0 = 0.f, a1 = 0.f, a2 = 0.f, a3 = 0.f;
    float b0 = 0.f, b1 = 0.f, b2 = 0.f, b3 = 0.f;
    if (n < nend) {
      int ra = rowsA ? rowsA[n] : n;
      int rb = rowsB ? rowsB[n] : n;
      ushort4 ua = *(const ushort4*)(A + (size_t)ra * K1 + k1_0 + kk4);
      ushort4 ub = *(const ushort4*)(B + (size_t)rb * K2 + k2_0 + kk4);
      a0 = b2f(ua.x); a1 = b2f(ua.y); a2 = b2f(ua.z); a3 = b2f(ua.w);
      b0 = b2f(ub.x); b1 = b2f(ub.y); b2 = b2f(ub.z); b3 = b2f(ub.w);
    }
    As[nn_][kk4] = a0; As[nn_][kk4 + 1] = a1; As[nn_][kk4 + 2] = a2; As[nn_][kk4 + 3] = a3;
    Bs[nn_][kk4] = b0; Bs[nn_][kk4 + 1] = b1; Bs[nn_][kk4 + 2] = b2; Bs[nn_][kk4 + 3] = b3;
    __syncthreads();
#pragma unroll
    for (int nn = 0; nn < 16; ++nn) {
      float4 a = *(const float4*)&As[nn][ty * 4];
      float4 b = *(const float4*)&Bs[nn][tx * 4];
      float av[4] = {a.x, a.y, a.z, a.w};
      float bv[4] = {b.x, b.y, b.z, b.w};
#pragma unroll
      for (int i = 0; i < 4; ++i)
#pragma unroll
        for (int j = 0; j < 4; ++j) acc[i][j] += av[i] * bv[j];
    }
    __syncthreads();
  }
#pragma unroll
  for (int i = 0; i < 4; ++i)
#pragma unroll
    for (int j = 0; j < 4; ++j)
      atomicAdd(&C[(long)(k1_0 + ty * 4 + i) * K2 + k2_0 + tx * 4 + j], acc[i][j]);
}

// ---------------- CSR build ----------------
__global__ void hist_kernel(const int* __restrict__ tgt, int* __restrict__ counts,
                            int nE, int ntgt) {
  int t = blockIdx.y;
  int e = blockIdx.x * 256 + threadIdx.x;
  if (e < nE) atomicAdd(&counts[t * ntgt + tgt[(long)t * nE + e]], 1);
}

__global__ __launch_bounds__(1024) void scan_kernel(const int* __restrict__ counts_all,
                                                    int* __restrict__ offs_all,
                                                    int* __restrict__ cursor_all, int n) {
  __shared__ int lsum[1024];
  int ty = blockIdx.x;
  const int* counts = counts_all + (long)ty * n;
  int* offs = offs_all + (long)ty * (n + 1);
  int* cursor = cursor_all + (long)ty * n;
  int t = threadIdx.x;
  int chunk = (n + 1023) >> 10;
  int base = t * chunk;
  int s = 0;
  for (int i = 0; i < chunk; ++i) {
    int idx = base + i;
    if (idx < n) s += counts[idx];
  }
  lsum[t] = s;
  __syncthreads();
  for (int off = 1; off < 1024; off <<= 1) {
    int v = (t >= off) ? lsum[t - off] : 0;
    __syncthreads();
    lsum[t] += v;
    __syncthreads();
  }
  int run = lsum[t] - s;
  for (int i = 0; i < chunk; ++i) {
    int idx = base + i;
    if (idx < n) {
      offs[idx] = run;
      cursor[idx] = run;
      run += counts[idx];
    }
  }
  if (t == 1023) offs[n] = lsum[1023];
}

__global__ void scatter_kernel(const int* __restrict__ tgt, int* __restrict__ cursor,
                               int* __restrict__ eorder, int nE, int ntgt) {
  int t = blockIdx.y;
  int e = blockIdx.x * 256 + threadIdx.x;
  if (e < nE) {
    int tv = tgt[(long)t * nE + e];
    int p = atomicAdd(&cursor[t * ntgt + tv], 1);
    eorder[(long)t * nE + p] = e;
  }
}

// ---------------- conv1: fused GATv2 (bf16 in/out) ----------------
__global__ __launch_bounds__(256) void conv1_agg(const ushortT* __restrict__ l,
                                                 const ushortT* __restrict__ r,
                                                 const float* __restrict__ a1t,
                                                 const int* __restrict__ src,
                                                 const int* __restrict__ eorder,
                                                 const int* __restrict__ offs,
                                                 ushortT* __restrict__ hout, int ntgt) {
  int wid = threadIdx.x >> 6, lane = threadIdx.x & 63;
  int v = blockIdx.x * 4 + wid;
  if (v >= ntgt) return;
  ushort4 ru = *(const ushort4*)(r + (size_t)v * 256 + lane * 4);
  float rx = b2f(ru.x), ry = b2f(ru.y), rz = b2f(ru.z), rw = b2f(ru.w);
  const float4 aa = *(const float4*)(a1t + lane * 4);
  int beg = offs[v], end = offs[v + 1];
  float ax = 0.f, ay = 0.f, az = 0.f, aw = 0.f, den = 0.f;
  for (int p = beg; p < end; ++p) {
    int e = eorder[p];
    int u = src[e];
    ushort4 lu = *(const ushort4*)(l + (size_t)u * 256 + lane * 4);
    float lx = b2f(lu.x), ly = b2f(lu.y), lz = b2f(lu.z), lw = b2f(lu.w);
    float s = lrelu(lx + rx) * aa.x + lrelu(ly + ry) * aa.y +
              lrelu(lz + rz) * aa.z + lrelu(lw + rw) * aa.w;
#pragma unroll
    for (int m = 1; m < 16; m <<= 1) s += __shfl_xor(s, m, 64);
    float w = expf(s);
    ax += w * lx; ay += w * ly; az += w * lz; aw += w * lw;
    den += w;
  }
  float inv = (end > beg) ? 1.f / den : 0.f;
  ushort4 o;
  o.x = f2b(fmaxf(ax * inv, 0.f));
  o.y = f2b(fmaxf(ay * inv, 0.f));
  o.z = f2b(fmaxf(az * inv, 0.f));
  o.w = f2b(fmaxf(aw * inv, 0.f));
  *(ushort4*)(hout + (size_t)v * 256 + lane * 4) = o;
}

// ---------------- softmax (f32 logits -> bf16 S) + entropy ----------------
__global__ __launch_bounds__(256) void softmax_ent(const float* __restrict__ logits,
                                                   ushortT* __restrict__ Sb, int nrows,
                                                   float inv_n, float* __restrict__ ent_slots) {
  int wid = threadIdx.x >> 6, lane = threadIdx.x & 63;
  int v = blockIdx.x * 4 + wid;
  if (v >= nrows) return;
  const float* row = logits + (size_t)v * 128;
  float x0 = row[lane], x1 = row[lane + 64];
  float m = fmaxf(x0, x1);
#pragma unroll
  for (int sh = 1; sh < 64; sh <<= 1) m = fmaxf(m, __shfl_xor(m, sh, 64));
  float e0 = expf(x0 - m), e1 = expf(x1 - m);
  float s = e0 + e1;
  float t = e0 * (x0 - m) + e1 * (x1 - m);
#pragma unroll
  for (int sh = 1; sh < 64; sh <<= 1) {
    s += __shfl_xor(s, sh, 64);
    t += __shfl_xor(t, sh, 64);
  }
  float inv = 1.f / s;
  Sb[(size_t)v * 128 + lane] = f2b(e0 * inv);
  Sb[(size_t)v * 128 + lane + 64] = f2b(e1 * inv);
  if (lane == 0) {
    float ent = logf(s) - t / s;
    atomicAdd(&ent_slots[blockIdx.x & 255], ent * inv_n);
  }
}

// ---------------- link loss ----------------
__global__ __launch_bounds__(256) void link_kernel(const float* __restrict__ Apool,
                                                   const float* __restrict__ Mp,
                                                   const float* __restrict__ Mt,
                                                   float Ef, float scale,
                                                   float* __restrict__ loss) {
  __shared__ float red[256];
  int t = threadIdx.x;
  float s = 0.f;
  for (int i = t; i < 16384; i += 256) s += Mp[i] * Mt[i];
  if (t < 128) s -= 2.f * Apool[t * 129];
  red[t] = s;
  __syncthreads();
  for (int sh = 128; sh > 0; sh >>= 1) {
    if (t < sh) red[t] += red[t + sh];
    __syncthreads();
  }
  if (t == 0) {
    float norm2 = Ef + red[0];
    atomicAdd(loss, sqrtf(fmaxf(norm2, 0.f) + 1e-12f) * scale);
  }
}

// ---------------- conv2 dense attention ----------------
__global__ __launch_bounds__(256) void conv2_attn(const float* __restrict__ l2_all,
                                                  const float* __restrict__ r2_all,
                                                  const float* __restrict__ Apool_all,
                                                  const float* __restrict__ a2_all,
                                                  float* __restrict__ attn_out) {
  __shared__ float r2row[256], a2s[256], sc[512];
  int j = blockIdx.x;
  int t = blockIdx.y;
  int tid = threadIdx.x;
  const float* l2 = l2_all + (long)t * 32768;
  const float* Apool = Apool_all + (long)t * 16384;
  r2row[tid] = r2_all[(long)t * 32768 + j * 256 + tid];
  a2s[tid] = a2_all[t * 256 + tid];
  __syncthreads();
#pragma unroll
  for (int p = tid; p < 512; p += 256) {
    int i = p >> 2, h = p & 3;
    const float* lr_ = l2 + i * 256 + h * 64;
    const float* rr_ = r2row + h * 64;
    const float* av_ = a2s + h * 64;
    float s = 0.f;
    for (int c = 0; c < 64; ++c) {
      float x = lr_[c] + rr_[c];
      s += (x > 0.f ? x : 0.2f * x) * av_[c];
    }
    sc[p] = (Apool[i * 128 + j] > 0.f) ? s : -1e9f;
  }
  __syncthreads();
  int h = tid >> 6, lane = tid & 63;
  float v0 = sc[lane * 4 + h], v1 = sc[(lane + 64) * 4 + h];
  float m = fmaxf(v0, v1);
#pragma unroll
  for (int sh = 1; sh < 64; sh <<= 1) m = fmaxf(m, __shfl_xor(m, sh, 64));
  float e0 = expf(v0 - m), e1 = expf(v1 - m);
  float s = e0 + e1;
#pragma unroll
  for (int sh = 1; sh < 64; sh <<= 1) s += __shfl_xor(s, sh, 64);
  float inv = 1.f / s;
  attn_out[(long)t * 65536 + (long)lane * 512 + j * 4 + h] = e0 * inv;
  attn_out[(long)t * 65536 + (long)(lane + 64) * 512 + j * 4 + h] = e1 * inv;
}

// ---------------- classifier ----------------
__global__ __launch_bounds__(256) void classifier(const float* __restrict__ p_all,
                                                  const float* __restrict__ Wcls,
                                                  const float* __restrict__ bcls,
                                                  float* __restrict__ out, int nrows) {
  int wid = threadIdx.x >> 6, lane = threadIdx.x & 63;
  int rrow = blockIdx.x * 4 + wid;
  if (rrow >= nrows) return;
  const float4 w = *(const float4*)(Wcls + lane * 4);
  const float4 x = *(const float4*)(p_all + (long)rrow * 256 + lane * 4);
  float s = x.x * w.x + x.y * w.y + x.z * w.z + x.w * w.w;
#pragma unroll
  for (int sh = 1; sh < 64; sh <<= 1) s += __shfl_xor(s, sh, 64);
  if (lane == 0) out[rrow] = 1.f / (1.f + expf(-(s + bcls[0])));
}

__global__ void finalize_loss(const float* __restrict__ red_buf, float* __restrict__ out896) {
  __shared__ float red[256];
  int t = threadIdx.x;
  red[t] = red_buf[t];
  __syncthreads();
  for (int sh = 128; sh > 0; sh >>= 1) {
    if (t < sh) red[t] += red[t + sh];
    __syncthreads();
  }
  if (t == 0) out896[0] = red[0] + red_buf[256];
}

// =====================================================================
extern "C" void kernel_launch(void* const* d_in, const int* in_sizes, int n_in,
                              void* d_out, int out_size, void* d_ws, size_t ws_size,
                              hipStream_t stream) {
  (void)in_sizes; (void)n_in; (void)out_size; (void)ws_size;
  const float* x_pkg  = (const float*)d_in[0];
  const float* x_tgt  = (const float*)d_in[1];
  const int* src_idx  = (const int*)d_in[2];
  const int* tgt_idx  = (const int*)d_in[3];
  const float* W1s    = (const float*)d_in[4];
  const float* W1t    = (const float*)d_in[5];
  const float* a1     = (const float*)d_in[6];
  const float* Wpkg   = (const float*)d_in[7];
  const float* Wassign= (const float*)d_in[8];
  const float* W2s    = (const float*)d_in[9];
  const float* W2t    = (const float*)d_in[10];
  const float* a2     = (const float*)d_in[11];
  const float* Wcls   = (const float*)d_in[12];
  const float* bcls   = (const float*)d_in[13];
  float* out = (float*)d_out;

  char* wp = (char*)d_ws;
  auto alloc = [&](size_t bytes) -> char* {
    char* r = wp;
    wp += (bytes + 255) & ~(size_t)255;
    return r;
  };
  // persistent
  ushortT* x_pkg_bf = (ushortT*)alloc((size_t)MP_PKG * KP_IN * 2);
  ushortT* h_pkg_bf = (ushortT*)alloc((size_t)MP_PKG * 256 * 2);
  ushortT* S_pkg_bf = (ushortT*)alloc((size_t)MP_PKG * 128 * 2);
  float* p_buf      = (float*)alloc((size_t)7 * 128 * 256 * 4);
  float* M_pkg      = (float*)alloc(16384 * 4);
  float* Apool      = (float*)alloc((size_t)NTYPES * 16384 * 4);
  ushortT* WpkgT    = (ushortT*)alloc((size_t)256 * KP_IN * 2);
  ushortT* W1sT     = (ushortT*)alloc((size_t)NTYPES * 256 * KP_IN * 2);
  ushortT* W1tT     = (ushortT*)alloc((size_t)NTYPES * 256 * KP_IN * 2);
  ushortT* WassT    = (ushortT*)alloc((size_t)7 * 128 * 256 * 2);
  int* counts       = (int*)alloc((size_t)NTYPES * NTGT * 4);
  int* offs         = (int*)alloc((size_t)NTYPES * (NTGT + 1) * 4);
  int* cursor       = (int*)alloc((size_t)NTYPES * NTGT * 4);
  int* eorder       = (int*)alloc((size_t)NTYPES * NEDGE * 4);
  float* red_buf    = (float*)alloc(257 * 4);
  float* l2_all     = (float*)alloc((size_t)NTYPES * 32768 * 4);
  float* r2_all     = (float*)alloc((size_t)NTYPES * 32768 * 4);
  // per-type scratch (reused each iteration)
  ushortT* x_t_bf   = (ushortT*)alloc((size_t)MP_TGT * KP_IN * 2);
  ushortT* l_bf     = (ushortT*)alloc((size_t)MP_PKG * 256 * 2);
  ushortT* r_bf     = (ushortT*)alloc((size_t)MP_TGT * 256 * 2);
  ushortT* h_t_bf   = (ushortT*)alloc((size_t)MP_TGT * 256 * 2);
  float* logits     = (float*)alloc((size_t)NTGT * 128 * 4);
  ushortT* S_t_bf   = (ushortT*)alloc((size_t)MP_TGT * 128 * 2);
  float* Mt         = (float*)alloc(16384 * 4);
  float* ent_slots  = red_buf;
  float* loss_acc   = red_buf + 256;

  dim3 blk(256);

  // --- init atomic targets ---
  zero_f32<<<dim3(64), blk, 0, stream>>>(p_buf, 7 * 128 * 256);
  zero_f32<<<dim3(16), blk, 0, stream>>>(M_pkg, 16384);
  zero_f32<<<dim3(96), blk, 0, stream>>>(Apool, NTYPES * 16384);
  zero_f32<<<dim3(1), blk, 0, stream>>>(red_buf, 257);
  zero_i32<<<dim3(180), blk, 0, stream>>>(counts, NTYPES * NTGT);

  // --- conversions ---
  convert_pad<<<dim3((NPKG * (KP_IN / 4) + 255) / 256), blk, 0, stream>>>(
      x_pkg, x_pkg_bf, NPKG, INDIM, KP_IN);
  wtrans<<<dim3((256 * KP_IN + 255) / 256, 1), blk, 0, stream>>>(Wpkg, WpkgT, INDIM, 256, KP_IN);
  wtrans<<<dim3((256 * KP_IN + 255) / 256, NTYPES), blk, 0, stream>>>(W1s, W1sT, INDIM, 256, KP_IN);
  wtrans<<<dim3((256 * KP_IN + 255) / 256, NTYPES), blk, 0, stream>>>(W1t, W1tT, INDIM, 256, KP_IN);
  wtrans<<<dim3((128 * 256 + 255) / 256, 7), blk, 0, stream>>>(Wassign, WassT, 256, 128, 256);

  // --- CSR ---
  hist_kernel<<<dim3(391, NTYPES), blk, 0, stream>>>(tgt_idx, counts, NEDGE, NTGT);
  scan_kernel<<<dim3(NTYPES), dim3(1024), 0, stream>>>(counts, offs, cursor, NTGT);
  scatter_kernel<<<dim3(391, NTYPES), blk, 0, stream>>>(tgt_idx, cursor, eorder, NEDGE, NTGT);

  // --- package branch ---
  gemm_mfma<true, false, true><<<dim3(2, 157), blk, 0, stream>>>(
      x_pkg_bf, WpkgT, nullptr, h_pkg_bf, NPKG, KP_IN, 256);
  gemm_mfma<false, true, false><<<dim3(1, 157), blk, 0, stream>>>(
      h_pkg_bf, WassT, logits, nullptr, NPKG, 256, 128);
  softmax_ent<<<dim3(5000), blk, 0, stream>>>(logits, S_pkg_bf, NPKG, 1.f / NPKG, ent_slots);
  gemm_tn_bf<<<dim3(4, 2, 40), blk, 0, stream>>>(S_pkg_bf, h_pkg_bf, p_buf,
                                                 nullptr, nullptr, NPKG, 128, 256, 512);
  gemm_tn_bf<<<dim3(2, 2, 40), blk, 0, stream>>>(S_pkg_bf, S_pkg_bf, M_pkg,
                                                 nullptr, nullptr, NPKG, 128, 128, 512);

  // --- per edge type ---
  for (int t = 0; t < NTYPES; ++t) {
    const int* srct = src_idx + (long)t * NEDGE;
    const int* tgtt = tgt_idx + (long)t * NEDGE;
    convert_pad<<<dim3((NTGT * (KP_IN / 4) + 255) / 256), blk, 0, stream>>>(
        x_tgt + (size_t)t * NTGT * INDIM, x_t_bf, NTGT, INDIM, KP_IN);
    gemm_mfma<false, false, true><<<dim3(2, 157), blk, 0, stream>>>(
        x_pkg_bf, W1sT + (size_t)t * 256 * KP_IN, nullptr, l_bf, NPKG, KP_IN, 256);
    gemm_mfma<false, false, true><<<dim3(2, 235), blk, 0, stream>>>(
        x_t_bf, W1tT + (size_t)t * 256 * KP_IN, nullptr, r_bf, NTGT, KP_IN, 256);
    conv1_agg<<<dim3(7500), blk, 0, stream>>>(l_bf, r_bf, a1 + t * 256, srct,
                                              eorder + (long)t * NEDGE,
                                              offs + (long)t * (NTGT + 1), h_t_bf, NTGT);
    gemm_mfma<false, true, false><<<dim3(1, 235), blk, 0, stream>>>(
        h_t_bf, WassT + (size_t)(t + 1) * 128 * 256, logits, nullptr, NTGT, 256, 128);
    softmax_ent<<<dim3(7500), blk, 0, stream>>>(logits, S_t_bf, NTGT, 1.f / NTGT, ent_slots);
    gemm_tn_bf<<<dim3(4, 2, 59), blk, 0, stream>>>(S_t_bf, h_t_bf, p_buf + (size_t)(t + 1) * 32768,
                                                   nullptr, nullptr, NTGT, 128, 256, 512);
    zero_f32<<<dim3(16), blk, 0, stream>>>(Mt, 16384);
    gemm_tn_bf<<<dim3(2, 2, 59), blk, 0, stream>>>(S_t_bf, S_t_bf, Mt,
                                                   nullptr, nullptr, NTGT, 128, 128, 512);
    gemm_tn_bf<<<dim3(2, 2, 196), blk, 0, stream>>>(S_pkg_bf, S_t_bf, Apool + (size_t)t * 16384,
                                                    srct, tgtt, NEDGE, 128, 128, 512);
    link_kernel<<<dim3(1), blk, 0, stream>>>(Apool + (size_t)t * 16384, M_pkg, Mt,
                                             (float)NEDGE, 1.f / ((float)NPKG * (float)NTGT),
                                             loss_acc);
  }

  // --- conv2 (tiny f32 gemms) + attention ---
  gemm128<false><<<dim3(2, 1, NTYPES), blk, 0, stream>>>(p_buf, W2s, l2_all, 128, 256, 256,
                                                         0, 65536, 32768);
  gemm128<false><<<dim3(2, 1, NTYPES), blk, 0, stream>>>(p_buf + 32768, W2t, r2_all, 128, 256, 256,
                                                         32768, 65536, 32768);
  conv2_attn<<<dim3(128, NTYPES), blk, 0, stream>>>(l2_all, r2_all, Apool, a2, out + 897);

  // --- classifier + loss ---
  classifier<<<dim3(224), blk, 0, stream>>>(p_buf, Wcls, bcls, out, 896);
  finalize_loss<<<dim3(1), blk, 0, stream>>>(red_buf, out + 896);
}

// Round 3
// 2045.187 us; speedup vs baseline: 3.1531x; 1.5616x over previous
//
#include <hip/hip_runtime.h>
#include <math.h>

#define NPKG   20000
#define NTGT   30000
#define NEDGE  100000
#define NTYPES 6
#define INDIM  400
#define KP_IN  416      // INDIM padded to mult of 32
#define MP_PKG 20096    // 157*128
#define MP_TGT 30080    // 235*128

#define LSTR   ((size_t)MP_PKG * 256)   // l_bf per-type stride (elems)
#define RSTR   ((size_t)MP_TGT * 256)   // r_bf / h_t per-type stride
#define XSTR   ((size_t)MP_TGT * KP_IN) // x_t_bf per-type stride
#define LOGSTR ((size_t)MP_TGT * 128)   // logits per-slot stride (f32)
#define SSTR   ((size_t)MP_TGT * 128)   // S per-slot stride (bf16)
#define WSTR   ((size_t)256 * KP_IN)    // weight slot stride

typedef unsigned short ushortT;
typedef __attribute__((ext_vector_type(8))) short bf16x8;
typedef __attribute__((ext_vector_type(4))) float f32x4;

__device__ __forceinline__ float lrelu(float x) { return x > 0.f ? x : 0.2f * x; }
__device__ __forceinline__ float b2f(ushortT u) {
  union { unsigned int i; float f; } x; x.i = ((unsigned int)u) << 16; return x.f;
}
__device__ __forceinline__ ushortT f2b(float f) {
  unsigned int u = __float_as_uint(f);
  unsigned int r = (u + 0x7FFFu + ((u >> 16) & 1u)) >> 16;
  return (ushortT)r;
}

#define GLL16(g, l)                                                            \
  __builtin_amdgcn_global_load_lds(                                            \
      (const __attribute__((address_space(1))) void*)(g),                      \
      (__attribute__((address_space(3))) void*)(l), 16, 0, 0)

// ---------------- utility ----------------
__global__ void zero_f32(float* __restrict__ p, long n) {
  long i = blockIdx.x * 256 + threadIdx.x, st = (long)gridDim.x * 256;
  for (; i < n; i += st) p[i] = 0.f;
}

// f32 [M,K] -> bf16 [*, Kp]; batched over blockIdx.y via strides
__global__ void convert_pad(const float* __restrict__ src, ushortT* __restrict__ dst,
                            int M, int K, int Kp, long srcStride, long dstStride) {
  long z = blockIdx.y;
  const float* s = src + z * srcStride;
  ushortT* d = dst + z * dstStride;
  int idx = blockIdx.x * 256 + threadIdx.x;
  int q = Kp >> 2;
  int row = idx / q, c4 = (idx - row * q) * 4;
  if (row >= M) return;
  float4 v = make_float4(0.f, 0.f, 0.f, 0.f);
  if (c4 < K) v = *(const float4*)(s + (size_t)row * K + c4);  // K mult of 4
  ushort4 o;
  o.x = f2b(v.x); o.y = f2b(v.y); o.z = f2b(v.z); o.w = f2b(v.w);
  *(ushort4*)(d + (size_t)row * Kp + c4) = o;
}

// 13-way batched weight transpose: slots 0..5 = W1s[t], 6 = Wpkg, 7..12 = W1t[t]
__global__ void wtrans13(const float* __restrict__ W1s, const float* __restrict__ Wpkg,
                         const float* __restrict__ W1t, ushortT* __restrict__ WT) {
  int z = blockIdx.y;
  const float* Wb = (z < 6) ? (W1s + (size_t)z * INDIM * 256)
                  : (z == 6) ? Wpkg
                  : (W1t + (size_t)(z - 7) * INDIM * 256);
  ushortT* WTb = WT + (size_t)z * WSTR;
  int idx = blockIdx.x * 256 + threadIdx.x;
  if (idx >= 256 * KP_IN) return;
  int n = idx / KP_IN, k = idx - n * KP_IN;
  WTb[idx] = (k < INDIM) ? f2b(Wb[(size_t)k * 256 + n]) : (ushortT)0;
}

// Wassign [7][256][128] -> [7][128][256] bf16
__global__ void wtransAss(const float* __restrict__ W, ushortT* __restrict__ WT) {
  int z = blockIdx.y;
  const float* Wb = W + (size_t)z * 256 * 128;
  ushortT* WTb = WT + (size_t)z * 128 * 256;
  int idx = blockIdx.x * 256 + threadIdx.x;
  if (idx >= 128 * 256) return;
  int n = idx >> 8, k = idx & 255;
  WTb[idx] = f2b(Wb[(size_t)k * 128 + n]);
}

// ---------------- batched MFMA GEMM ----------------
struct MfmaBatch {
  const ushortT* A[8];
  const ushortT* BT[8];
  void* C[8];
  int M[8];
  int relu[8];
};

template<bool WF32>
__global__ __launch_bounds__(256) void gemm_mfma_b(MfmaBatch d, int Kp, int N) {
  const int z = blockIdx.z;
  const int M = d.M[z];
  const int m0 = blockIdx.y * 128;
  if (m0 >= M) return;
  const ushortT* A = d.A[z];
  const ushortT* BT = d.BT[z];
  const int relu = d.relu[z];
  __shared__ ushortT As[128 * 32];
  __shared__ ushortT Bs[128 * 32];
  const int tid = threadIdx.x;
  const int wave = tid >> 6, lane = tid & 63;
  const int lr = lane & 15, hk = lane >> 4;
  const int am = (wave >> 1) * 64;
  const int bn = (wave & 1) * 64;
  const int n0 = blockIdx.x * 128;

  const int row1 = tid >> 2, cg = (tid & 3) * 8;
  const int row2 = row1 + 64;
  ushortT* ldsA1 = As + ((tid >> 6) << 9);
  ushortT* ldsA2 = As + 2048 + ((tid >> 6) << 9);
  ushortT* ldsB1 = Bs + ((tid >> 6) << 9);
  ushortT* ldsB2 = Bs + 2048 + ((tid >> 6) << 9);
  const ushortT* gA1 = A + (size_t)(m0 + row1) * Kp + cg;
  const ushortT* gA2 = A + (size_t)(m0 + row2) * Kp + cg;
  const ushortT* gB1 = BT + (size_t)(n0 + row1) * Kp + cg;
  const ushortT* gB2 = BT + (size_t)(n0 + row2) * Kp + cg;

  f32x4 acc[4][4];
#pragma unroll
  for (int i = 0; i < 4; ++i)
#pragma unroll
    for (int j = 0; j < 4; ++j) acc[i][j] = (f32x4)(0.f);

  const int nk = Kp >> 5;
  for (int kt = 0; kt < nk; ++kt) {
    const int k0 = kt << 5;
    GLL16(gA1 + k0, ldsA1);
    GLL16(gA2 + k0, ldsA2);
    GLL16(gB1 + k0, ldsB1);
    GLL16(gB2 + k0, ldsB2);
    __syncthreads();
    bf16x8 af[4], bfr[4];
#pragma unroll
    for (int i = 0; i < 4; ++i)
      af[i] = *(const bf16x8*)(As + (size_t)(am + i * 16 + lr) * 32 + hk * 8);
#pragma unroll
    for (int j = 0; j < 4; ++j)
      bfr[j] = *(const bf16x8*)(Bs + (size_t)(bn + j * 16 + lr) * 32 + hk * 8);
#pragma unroll
    for (int i = 0; i < 4; ++i)
#pragma unroll
      for (int j = 0; j < 4; ++j)
        acc[i][j] = __builtin_amdgcn_mfma_f32_16x16x32_bf16(af[i], bfr[j], acc[i][j], 0, 0, 0);
    __syncthreads();
  }

#pragma unroll
  for (int i = 0; i < 4; ++i) {
#pragma unroll
    for (int reg = 0; reg < 4; ++reg) {
      int row = m0 + am + i * 16 + hk * 4 + reg;
      if (row < M) {
#pragma unroll
        for (int j = 0; j < 4; ++j) {
          int col = n0 + bn + j * 16 + lr;
          float v = acc[i][j][reg];
          if (relu) v = fmaxf(v, 0.f);
          if (WF32) ((float*)d.C[z])[(size_t)row * N + col] = v;
          else      ((ushortT*)d.C[z])[(size_t)row * N + col] = f2b(v);
        }
      }
    }
  }
}

// ---------------- batched GEMM-TN bf16 (split-K atomic) ----------------
struct TnBatch {
  const ushortT* A[8];
  const ushortT* B[8];
  float* C[8];
  const int* rA[8];
  const int* rB[8];
  int N[8];
};

__global__ __launch_bounds__(256) void gemm_tn_b(TnBatch d, int K1, int K2,
                                                 int chunk, int nchunk) {
  const int mat = blockIdx.z / nchunk;
  const int ci = blockIdx.z - mat * nchunk;
  const int N = d.N[mat];
  const int nbeg = ci * chunk;
  if (nbeg >= N) return;
  const int nend = min(N, nbeg + chunk);
  const ushortT* A = d.A[mat];
  const ushortT* B = d.B[mat];
  const int* rowsA = d.rA[mat];
  const int* rowsB = d.rB[mat];
  __shared__ __align__(16) float As[16][68];
  __shared__ __align__(16) float Bs[16][68];
  const int tid = threadIdx.x;
  const int tx = tid & 15, ty = tid >> 4;
  const int k2_0 = blockIdx.x * 64, k1_0 = blockIdx.y * 64;
  float acc[4][4] = {{0.f}};
  const int nn_ = tid >> 4, kk4 = (tid & 15) * 4;

  for (int nb = nbeg; nb < nend; nb += 16) {
    int n = nb + nn_;
    float a0 = 0.f, a1 = 0.f, a2 = 0.f, a3 = 0.f;
    float b0 = 0.f, b1 = 0.f, b2 = 0.f, b3 = 0.f;
    if (n < nend) {
      int ra = rowsA ? rowsA[n] : n;
      int rb = rowsB ? rowsB[n] : n;
      ushort4 ua = *(const ushort4*)(A + (size_t)ra * K1 + k1_0 + kk4);
      ushort4 ub = *(const ushort4*)(B + (size_t)rb * K2 + k2_0 + kk4);
      a0 = b2f(ua.x); a1 = b2f(ua.y); a2 = b2f(ua.z); a3 = b2f(ua.w);
      b0 = b2f(ub.x); b1 = b2f(ub.y); b2 = b2f(ub.z); b3 = b2f(ub.w);
    }
    As[nn_][kk4] = a0; As[nn_][kk4 + 1] = a1; As[nn_][kk4 + 2] = a2; As[nn_][kk4 + 3] = a3;
    Bs[nn_][kk4] = b0; Bs[nn_][kk4 + 1] = b1; Bs[nn_][kk4 + 2] = b2; Bs[nn_][kk4 + 3] = b3;
    __syncthreads();
#pragma unroll
    for (int nn = 0; nn < 16; ++nn) {
      float4 a = *(const float4*)&As[nn][ty * 4];
      float4 b = *(const float4*)&Bs[nn][tx * 4];
      float av[4] = {a.x, a.y, a.z, a.w};
      float bv[4] = {b.x, b.y, b.z, b.w};
#pragma unroll
      for (int i = 0; i < 4; ++i)
#pragma unroll
        for (int j = 0; j < 4; ++j) acc[i][j] += av[i] * bv[j];
    }
    __syncthreads();
  }
#pragma unroll
  for (int i = 0; i < 4; ++i)
#pragma unroll
    for (int j = 0; j < 4; ++j)
      atomicAdd(&d.C[mat][(size_t)(k1_0 + ty * 4 + i) * K2 + k2_0 + tx * 4 + j], acc[i][j]);
}

// ---------------- CSR build ----------------
__global__ void hist_kernel(const int* __restrict__ tgt, int* __restrict__ counts,
                            int nE, int ntgt) {
  int t = blockIdx.y;
  int e = blockIdx.x * 256 + threadIdx.x;
  if (e < nE) atomicAdd(&counts[t * ntgt + tgt[(long)t * nE + e]], 1);
}

__global__ __launch_bounds__(1024) void scan_kernel(const int* __restrict__ counts_all,
                                                    int* __restrict__ offs_all,
                                                    int* __restrict__ cursor_all, int n) {
  __shared__ int lsum[1024];
  int ty = blockIdx.x;
  const int* counts = counts_all + (long)ty * n;
  int* offs = offs_all + (long)ty * (n + 1);
  int* cursor = cursor_all + (long)ty * n;
  int t = threadIdx.x;
  int chunk = (n + 1023) >> 10;
  int base = t * chunk;
  int s = 0;
  for (int i = 0; i < chunk; ++i) {
    int idx = base + i;
    if (idx < n) s += counts[idx];
  }
  lsum[t] = s;
  __syncthreads();
  for (int off = 1; off < 1024; off <<= 1) {
    int v = (t >= off) ? lsum[t - off] : 0;
    __syncthreads();
    lsum[t] += v;
    __syncthreads();
  }
  int run = lsum[t] - s;
  for (int i = 0; i < chunk; ++i) {
    int idx = base + i;
    if (idx < n) {
      offs[idx] = run;
      cursor[idx] = run;
      run += counts[idx];
    }
  }
  if (t == 1023) offs[n] = lsum[1023];
}

__global__ void scatter_kernel(const int* __restrict__ tgt, int* __restrict__ cursor,
                               int* __restrict__ eorder, int nE, int ntgt) {
  int t = blockIdx.y;
  int e = blockIdx.x * 256 + threadIdx.x;
  if (e < nE) {
    int tv = tgt[(long)t * nE + e];
    int p = atomicAdd(&cursor[t * ntgt + tv], 1);
    eorder[(long)t * nE + p] = e;
  }
}

// ---------------- conv1: fused GATv2 (bf16 in/out), batched over type ----------------
__global__ __launch_bounds__(256) void conv1_agg(const ushortT* __restrict__ l_all,
                                                 const ushortT* __restrict__ r_all,
                                                 const float* __restrict__ a1,
                                                 const int* __restrict__ src_all,
                                                 const int* __restrict__ eorder_all,
                                                 const int* __restrict__ offs_all,
                                                 ushortT* __restrict__ h_all) {
  int t = blockIdx.y;
  const ushortT* l = l_all + (size_t)t * LSTR;
  const ushortT* r = r_all + (size_t)t * RSTR;
  const float* a1t = a1 + t * 256;
  const int* src = src_all + (long)t * NEDGE;
  const int* eorder = eorder_all + (long)t * NEDGE;
  const int* offs = offs_all + (long)t * (NTGT + 1);
  ushortT* hout = h_all + (size_t)t * RSTR;

  int wid = threadIdx.x >> 6, lane = threadIdx.x & 63;
  int v = blockIdx.x * 4 + wid;
  if (v >= NTGT) return;
  ushort4 ru = *(const ushort4*)(r + (size_t)v * 256 + lane * 4);
  float rx = b2f(ru.x), ry = b2f(ru.y), rz = b2f(ru.z), rw = b2f(ru.w);
  const float4 aa = *(const float4*)(a1t + lane * 4);
  int beg = offs[v], end = offs[v + 1];
  float ax = 0.f, ay = 0.f, az = 0.f, aw = 0.f, den = 0.f;
  for (int p = beg; p < end; ++p) {
    int e = eorder[p];
    int u = src[e];
    ushort4 lu = *(const ushort4*)(l + (size_t)u * 256 + lane * 4);
    float lx = b2f(lu.x), ly = b2f(lu.y), lz = b2f(lu.z), lw = b2f(lu.w);
    float s = lrelu(lx + rx) * aa.x + lrelu(ly + ry) * aa.y +
              lrelu(lz + rz) * aa.z + lrelu(lw + rw) * aa.w;
#pragma unroll
    for (int m = 1; m < 16; m <<= 1) s += __shfl_xor(s, m, 64);
    float w = expf(s);
    ax += w * lx; ay += w * ly; az += w * lz; aw += w * lw;
    den += w;
  }
  float inv = (end > beg) ? 1.f / den : 0.f;
  ushort4 o;
  o.x = f2b(fmaxf(ax * inv, 0.f));
  o.y = f2b(fmaxf(ay * inv, 0.f));
  o.z = f2b(fmaxf(az * inv, 0.f));
  o.w = f2b(fmaxf(aw * inv, 0.f));
  *(ushort4*)(hout + (size_t)v * 256 + lane * 4) = o;
}

// ---------------- softmax (f32 logits -> bf16 S) + entropy, batched z=7 ----------------
__global__ __launch_bounds__(256) void softmax_ent(const float* __restrict__ logits_all,
                                                   ushortT* __restrict__ S_all,
                                                   float* __restrict__ ent_slots) {
  int z = blockIdx.y;
  int nrows = (z == 6) ? NPKG : NTGT;
  float inv_n = 1.f / (float)nrows;
  const float* logits = logits_all + (size_t)z * LOGSTR;
  ushortT* Sb = S_all + (size_t)z * SSTR;

  int wid = threadIdx.x >> 6, lane = threadIdx.x & 63;
  int v = blockIdx.x * 4 + wid;
  if (v >= nrows) return;
  const float* row = logits + (size_t)v * 128;
  float x0 = row[lane], x1 = row[lane + 64];
  float m = fmaxf(x0, x1);
#pragma unroll
  for (int sh = 1; sh < 64; sh <<= 1) m = fmaxf(m, __shfl_xor(m, sh, 64));
  float e0 = expf(x0 - m), e1 = expf(x1 - m);
  float s = e0 + e1;
  float t = e0 * (x0 - m) + e1 * (x1 - m);
#pragma unroll
  for (int sh = 1; sh < 64; sh <<= 1) {
    s += __shfl_xor(s, sh, 64);
    t += __shfl_xor(t, sh, 64);
  }
  float inv = 1.f / s;
  Sb[(size_t)v * 128 + lane] = f2b(e0 * inv);
  Sb[(size_t)v * 128 + lane + 64] = f2b(e1 * inv);
  if (lane == 0) {
    float ent = logf(s) - t / s;
    atomicAdd(&ent_slots[blockIdx.x & 255], ent * inv_n);
  }
}

// ---------------- link loss, batched grid(6) ----------------
__global__ __launch_bounds__(256) void link_kernel(const float* __restrict__ Apool_all,
                                                   const float* __restrict__ M_all,
                                                   float Ef, float scale,
                                                   float* __restrict__ loss) {
  __shared__ float red[256];
  int ty = blockIdx.x;
  const float* Apool = Apool_all + (size_t)ty * 16384;
  const float* Mp = M_all + (size_t)6 * 16384;
  const float* Mt = M_all + (size_t)ty * 16384;
  int t = threadIdx.x;
  float s = 0.f;
  for (int i = t; i < 16384; i += 256) s += Mp[i] * Mt[i];
  if (t < 128) s -= 2.f * Apool[t * 129];
  red[t] = s;
  __syncthreads();
  for (int sh = 128; sh > 0; sh >>= 1) {
    if (t < sh) red[t] += red[t + sh];
    __syncthreads();
  }
  if (t == 0) {
    float norm2 = Ef + red[0];
    atomicAdd(loss, sqrtf(fmaxf(norm2, 0.f) + 1e-12f) * scale);
  }
}

// ---------------- conv2 GEMMs, one launch z=12 ----------------
__global__ __launch_bounds__(256) void conv2_gemm(const float* __restrict__ p_buf,
                                                  const float* __restrict__ W2s,
                                                  const float* __restrict__ W2t,
                                                  float* __restrict__ l2r2) {
  const int z = blockIdx.z;
  const int sel = z / 6, t = z - sel * 6;
  const float* A = p_buf + (sel ? (size_t)(t + 1) * 32768 : 0);
  const float* B = (sel ? W2t : W2s) + (size_t)t * 65536;
  float* C = l2r2 + (size_t)sel * 196608 + (size_t)t * 32768;
  const int M = 128, K = 256, N = 256;
  __shared__ __align__(16) float As[16][136];
  __shared__ __align__(16) float Bs[16][136];
  const int tid = threadIdx.x;
  const int tx = tid & 15, ty = tid >> 4;
  const int n0 = blockIdx.x * 128;
  float acc[8][8];
#pragma unroll
  for (int i = 0; i < 8; ++i)
#pragma unroll
    for (int j = 0; j < 8; ++j) acc[i][j] = 0.f;
  for (int k0 = 0; k0 < K; k0 += 16) {
#pragma unroll
    for (int i = 0; i < 8; ++i) {
      int idx = tid + i * 256;
      int rr = idx >> 4, kk = idx & 15;
      As[kk][rr] = (rr < M) ? A[(size_t)rr * K + (k0 + kk)] : 0.f;
    }
#pragma unroll
    for (int i = 0; i < 8; ++i) {
      int idx = tid + i * 256;
      int kk = idx >> 7, nn = idx & 127;
      Bs[kk][nn] = B[(size_t)(k0 + kk) * N + (n0 + nn)];
    }
    __syncthreads();
#pragma unroll
    for (int kk = 0; kk < 16; ++kk) {
      float4 a0 = *(const float4*)&As[kk][ty * 8];
      float4 a1 = *(const float4*)&As[kk][ty * 8 + 4];
      float4 b0 = *(const float4*)&Bs[kk][tx * 8];
      float4 b1 = *(const float4*)&Bs[kk][tx * 8 + 4];
      float av[8] = {a0.x, a0.y, a0.z, a0.w, a1.x, a1.y, a1.z, a1.w};
      float bv[8] = {b0.x, b0.y, b0.z, b0.w, b1.x, b1.y, b1.z, b1.w};
#pragma unroll
      for (int i = 0; i < 8; ++i)
#pragma unroll
        for (int j = 0; j < 8; ++j) acc[i][j] += av[i] * bv[j];
    }
    __syncthreads();
  }
#pragma unroll
  for (int i = 0; i < 8; ++i) {
    int m = ty * 8 + i;
    if (m < M) {
#pragma unroll
      for (int j = 0; j < 8; ++j)
        C[(size_t)m * N + n0 + tx * 8 + j] = acc[i][j];
    }
  }
}

// ---------------- conv2 dense attention ----------------
__global__ __launch_bounds__(256) void conv2_attn(const float* __restrict__ l2_all,
                                                  const float* __restrict__ r2_all,
                                                  const float* __restrict__ Apool_all,
                                                  const float* __restrict__ a2_all,
                                                  float* __restrict__ attn_out) {
  __shared__ float r2row[256], a2s[256], sc[512];
  int j = blockIdx.x;
  int t = blockIdx.y;
  int tid = threadIdx.x;
  const float* l2 = l2_all + (long)t * 32768;
  const float* Apool = Apool_all + (long)t * 16384;
  r2row[tid] = r2_all[(long)t * 32768 + j * 256 + tid];
  a2s[tid] = a2_all[t * 256 + tid];
  __syncthreads();
#pragma unroll
  for (int p = tid; p < 512; p += 256) {
    int i = p >> 2, h = p & 3;
    const float* lr_ = l2 + i * 256 + h * 64;
    const float* rr_ = r2row + h * 64;
    const float* av_ = a2s + h * 64;
    float s = 0.f;
    for (int c = 0; c < 64; ++c) {
      float x = lr_[c] + rr_[c];
      s += (x > 0.f ? x : 0.2f * x) * av_[c];
    }
    sc[p] = (Apool[i * 128 + j] > 0.f) ? s : -1e9f;
  }
  __syncthreads();
  int h = tid >> 6, lane = tid & 63;
  float v0 = sc[lane * 4 + h], v1 = sc[(lane + 64) * 4 + h];
  float m = fmaxf(v0, v1);
#pragma unroll
  for (int sh = 1; sh < 64; sh <<= 1) m = fmaxf(m, __shfl_xor(m, sh, 64));
  float e0 = expf(v0 - m), e1 = expf(v1 - m);
  float s = e0 + e1;
#pragma unroll
  for (int sh = 1; sh < 64; sh <<= 1) s += __shfl_xor(s, sh, 64);
  float inv = 1.f / s;
  attn_out[(long)t * 65536 + (long)lane * 512 + j * 4 + h] = e0 * inv;
  attn_out[(long)t * 65536 + (long)(lane + 64) * 512 + j * 4 + h] = e1 * inv;
}

// ---------------- classifier ----------------
__global__ __launch_bounds__(256) void classifier(const float* __restrict__ p_all,
                                                  const float* __restrict__ Wcls,
                                                  const float* __restrict__ bcls,
                                                  float* __restrict__ out, int nrows) {
  int wid = threadIdx.x >> 6, lane = threadIdx.x & 63;
  int rrow = blockIdx.x * 4 + wid;
  if (rrow >= nrows) return;
  const float4 w = *(const float4*)(Wcls + lane * 4);
  const float4 x = *(const float4*)(p_all + (long)rrow * 256 + lane * 4);
  float s = x.x * w.x + x.y * w.y + x.z * w.z + x.w * w.w;
#pragma unroll
  for (int sh = 1; sh < 64; sh <<= 1) s += __shfl_xor(s, sh, 64);
  if (lane == 0) out[rrow] = 1.f / (1.f + expf(-(s + bcls[0])));
}

__global__ void finalize_loss(const float* __restrict__ red_buf, float* __restrict__ out896) {
  __shared__ float red[256];
  int t = threadIdx.x;
  red[t] = red_buf[t];
  __syncthreads();
  for (int sh = 128; sh > 0; sh >>= 1) {
    if (t < sh) red[t] += red[t + sh];
    __syncthreads();
  }
  if (t == 0) out896[0] = red[0] + red_buf[256];
}

// =====================================================================
extern "C" void kernel_launch(void* const* d_in, const int* in_sizes, int n_in,
                              void* d_out, int out_size, void* d_ws, size_t ws_size,
                              hipStream_t stream) {
  (void)in_sizes; (void)n_in; (void)out_size; (void)ws_size;
  const float* x_pkg  = (const float*)d_in[0];
  const float* x_tgt  = (const float*)d_in[1];
  const int* src_idx  = (const int*)d_in[2];
  const int* tgt_idx  = (const int*)d_in[3];
  const float* W1s    = (const float*)d_in[4];
  const float* W1t    = (const float*)d_in[5];
  const float* a1     = (const float*)d_in[6];
  const float* Wpkg   = (const float*)d_in[7];
  const float* Wassign= (const float*)d_in[8];
  const float* W2s    = (const float*)d_in[9];
  const float* W2t    = (const float*)d_in[10];
  const float* a2     = (const float*)d_in[11];
  const float* Wcls   = (const float*)d_in[12];
  const float* bcls   = (const float*)d_in[13];
  float* out = (float*)d_out;

  char* wp = (char*)d_ws;
  auto alloc = [&](size_t bytes) -> char* {
    char* r = wp;
    wp += (bytes + 255) & ~(size_t)255;
    return r;
  };
  // --- zero region (contiguous): p_buf, M_all, Apool, red_buf, counts ---
  float* p_buf   = (float*)alloc((size_t)7 * 32768 * 4);          // slot0=pkg, 1..6=types
  float* M_all   = (float*)alloc((size_t)7 * 16384 * 4);          // slots 0..5=types, 6=pkg
  float* Apool   = (float*)alloc((size_t)NTYPES * 16384 * 4);
  float* red_buf = (float*)alloc(257 * 4);
  int* counts    = (int*)alloc((size_t)NTYPES * NTGT * 4);
  long zero_n = ((char*)counts + (size_t)NTYPES * NTGT * 4 - (char*)p_buf) / 4;
  // --- rest ---
  int* offs      = (int*)alloc((size_t)NTYPES * (NTGT + 1) * 4);
  int* cursor    = (int*)alloc((size_t)NTYPES * NTGT * 4);
  int* eorder    = (int*)alloc((size_t)NTYPES * NEDGE * 4);
  ushortT* x_pkg_bf = (ushortT*)alloc((size_t)MP_PKG * KP_IN * 2);
  ushortT* x_t_bf   = (ushortT*)alloc((size_t)NTYPES * XSTR * 2);
  ushortT* WT_all   = (ushortT*)alloc((size_t)13 * WSTR * 2);     // 0..5 W1s, 6 Wpkg, 7..12 W1t
  ushortT* WassT    = (ushortT*)alloc((size_t)7 * 128 * 256 * 2); // slot0=pkg, 1..6=types
  ushortT* h_pkg_bf = (ushortT*)alloc((size_t)MP_PKG * 256 * 2);
  ushortT* l_bf     = (ushortT*)alloc((size_t)NTYPES * LSTR * 2);
  ushortT* r_bf     = (ushortT*)alloc((size_t)NTYPES * RSTR * 2);
  ushortT* h_t_bf   = (ushortT*)alloc((size_t)NTYPES * RSTR * 2);
  float* logits     = (float*)alloc((size_t)7 * LOGSTR * 4);      // slots 0..5=types, 6=pkg
  ushortT* S_all    = (ushortT*)alloc((size_t)7 * SSTR * 2);      // slots 0..5=types, 6=pkg
  float* l2r2       = (float*)alloc((size_t)12 * 32768 * 4);      // l2[6], then r2[6]
  float* ent_slots  = red_buf;
  float* loss_acc   = red_buf + 256;
  float* l2_all = l2r2;
  float* r2_all = l2r2 + (size_t)6 * 32768;

  dim3 blk(256);

  // 1. zero all atomic targets in one pass
  zero_f32<<<dim3(512), blk, 0, stream>>>(p_buf, zero_n);

  // 2-3. input conversions
  convert_pad<<<dim3((NPKG * (KP_IN / 4) + 255) / 256, 1), blk, 0, stream>>>(
      x_pkg, x_pkg_bf, NPKG, INDIM, KP_IN, 0, 0);
  convert_pad<<<dim3((NTGT * (KP_IN / 4) + 255) / 256, NTYPES), blk, 0, stream>>>(
      x_tgt, x_t_bf, NTGT, INDIM, KP_IN, (long)NTGT * INDIM, (long)XSTR);

  // 4-5. weight transposes
  wtrans13<<<dim3((256 * KP_IN + 255) / 256, 13), blk, 0, stream>>>(W1s, Wpkg, W1t, WT_all);
  wtransAss<<<dim3((128 * 256 + 255) / 256, 7), blk, 0, stream>>>(Wassign, WassT);

  // 6-8. CSR
  hist_kernel<<<dim3(391, NTYPES), blk, 0, stream>>>(tgt_idx, counts, NEDGE, NTGT);
  scan_kernel<<<dim3(NTYPES), dim3(1024), 0, stream>>>(counts, offs, cursor, NTGT);
  scatter_kernel<<<dim3(391, NTYPES), blk, 0, stream>>>(tgt_idx, cursor, eorder, NEDGE, NTGT);

  // 9. l-gemms (z=0..5) + h_pkg gemm (z=6), all A=x_pkg
  {
    MfmaBatch d{};
    for (int z = 0; z < 6; ++z) {
      d.A[z] = x_pkg_bf; d.BT[z] = WT_all + (size_t)z * WSTR;
      d.C[z] = l_bf + (size_t)z * LSTR; d.M[z] = NPKG; d.relu[z] = 0;
    }
    d.A[6] = x_pkg_bf; d.BT[6] = WT_all + (size_t)6 * WSTR;
    d.C[6] = h_pkg_bf; d.M[6] = NPKG; d.relu[6] = 1;
    d.A[7] = d.A[0]; d.BT[7] = d.BT[0]; d.C[7] = d.C[0]; d.M[7] = 0; d.relu[7] = 0;
    gemm_mfma_b<false><<<dim3(2, 157, 7), blk, 0, stream>>>(d, KP_IN, 256);
  }

  // 10. r-gemms (z=0..5)
  {
    MfmaBatch d{};
    for (int z = 0; z < 6; ++z) {
      d.A[z] = x_t_bf + (size_t)z * XSTR; d.BT[z] = WT_all + (size_t)(7 + z) * WSTR;
      d.C[z] = r_bf + (size_t)z * RSTR; d.M[z] = NTGT; d.relu[z] = 0;
    }
    for (int z = 6; z < 8; ++z) { d.A[z] = d.A[0]; d.BT[z] = d.BT[0]; d.C[z] = d.C[0]; d.M[z] = 0; d.relu[z] = 0; }
    gemm_mfma_b<false><<<dim3(2, 235, 6), blk, 0, stream>>>(d, KP_IN, 256);
  }

  // 11. conv1 (all types)
  conv1_agg<<<dim3(7500, NTYPES), blk, 0, stream>>>(l_bf, r_bf, a1, src_idx, eorder, offs, h_t_bf);

  // 12. assignment logits (z=0..5 types, z=6 pkg)
  {
    MfmaBatch d{};
    for (int z = 0; z < 6; ++z) {
      d.A[z] = h_t_bf + (size_t)z * RSTR; d.BT[z] = WassT + (size_t)(z + 1) * 128 * 256;
      d.C[z] = logits + (size_t)z * LOGSTR; d.M[z] = NTGT; d.relu[z] = 0;
    }
    d.A[6] = h_pkg_bf; d.BT[6] = WassT; d.C[6] = logits + (size_t)6 * LOGSTR;
    d.M[6] = NPKG; d.relu[6] = 0;
    d.A[7] = d.A[0]; d.BT[7] = d.BT[0]; d.C[7] = d.C[0]; d.M[7] = 0; d.relu[7] = 0;
    gemm_mfma_b<true><<<dim3(1, 235, 7), blk, 0, stream>>>(d, 256, 128);
  }

  // 13. softmax + entropy (z=0..6)
  softmax_ent<<<dim3(7500, 7), blk, 0, stream>>>(logits, S_all, ent_slots);

  // 14. pooled features P = S^T h (mats 0..5 types, 6 pkg)
  {
    TnBatch d{};
    for (int m = 0; m < 6; ++m) {
      d.A[m] = S_all + (size_t)m * SSTR; d.B[m] = h_t_bf + (size_t)m * RSTR;
      d.C[m] = p_buf + (size_t)(m + 1) * 32768;
      d.rA[m] = nullptr; d.rB[m] = nullptr; d.N[m] = NTGT;
    }
    d.A[6] = S_all + (size_t)6 * SSTR; d.B[6] = h_pkg_bf; d.C[6] = p_buf;
    d.rA[6] = nullptr; d.rB[6] = nullptr; d.N[6] = NPKG;
    d.A[7] = d.A[0]; d.B[7] = d.B[0]; d.C[7] = d.C[0]; d.rA[7] = nullptr; d.rB[7] = nullptr; d.N[7] = 0;
    gemm_tn_b<<<dim3(4, 2, 7 * 59), blk, 0, stream>>>(d, 128, 256, 512, 59);
  }

  // 15. M = S^T S (mats 0..5 types, 6 pkg)
  {
    TnBatch d{};
    for (int m = 0; m < 7; ++m) {
      const ushortT* S = S_all + (size_t)m * SSTR;
      d.A[m] = S; d.B[m] = S; d.C[m] = M_all + (size_t)m * 16384;
      d.rA[m] = nullptr; d.rB[m] = nullptr; d.N[m] = (m == 6) ? NPKG : NTGT;
    }
    d.A[7] = d.A[0]; d.B[7] = d.B[0]; d.C[7] = d.C[0]; d.rA[7] = nullptr; d.rB[7] = nullptr; d.N[7] = 0;
    gemm_tn_b<<<dim3(2, 2, 7 * 59), blk, 0, stream>>>(d, 128, 128, 512, 59);
  }

  // 16. Apool = gathered S_pkg^T S_t over edges (mats 0..5)
  {
    TnBatch d{};
    for (int m = 0; m < 6; ++m) {
      d.A[m] = S_all + (size_t)6 * SSTR; d.B[m] = S_all + (size_t)m * SSTR;
      d.C[m] = Apool + (size_t)m * 16384;
      d.rA[m] = src_idx + (long)m * NEDGE; d.rB[m] = tgt_idx + (long)m * NEDGE;
      d.N[m] = NEDGE;
    }
    for (int m = 6; m < 8; ++m) { d.A[m] = d.A[0]; d.B[m] = d.B[0]; d.C[m] = d.C[0]; d.rA[m] = nullptr; d.rB[m] = nullptr; d.N[m] = 0; }
    gemm_tn_b<<<dim3(2, 2, 6 * 196), blk, 0, stream>>>(d, 128, 128, 512, 196);
  }

  // 17. link losses
  link_kernel<<<dim3(6), blk, 0, stream>>>(Apool, M_all, (float)NEDGE,
                                           1.f / ((float)NPKG * (float)NTGT), loss_acc);

  // 18-19. conv2
  conv2_gemm<<<dim3(2, 1, 12), blk, 0, stream>>>(p_buf, W2s, W2t, l2r2);
  conv2_attn<<<dim3(128, NTYPES), blk, 0, stream>>>(l2_all, r2_all, Apool, a2, out + 897);

  // 20-21. classifier + loss
  classifier<<<dim3(224), blk, 0, stream>>>(p_buf, Wcls, bcls, out, 896);
  finalize_loss<<<dim3(1), blk, 0, stream>>>(red_buf, out + 896);
}